// Round 5
// baseline (482.517 us; speedup 1.0000x reference)
//
#include <hip/hip_runtime.h>
#include <math.h>

#define NFFT  16000   // = 128 * 125
#define NCCOL 125     // radix-5 axis (contiguous)
#define DFEAT 2048
#define TPB   1024
#define R2OFF 16000   // LDS offset: 64-entry w_128^j LUT (forward sign)
#define R5OFF 16064   // LDS offset: 125-entry w_125^k LUT (forward sign)
#define LDSN  16189   // total float2 elements in LDS

__device__ __forceinline__ float2 cmul(float2 a, float2 b) {
    return make_float2(a.x*b.x - a.y*b.y, a.x*b.y + a.y*b.x);
}
__device__ __forceinline__ float2 cmulc(float2 a, float2 b) {   // a * conj(b)
    return make_float2(a.x*b.x + a.y*b.y, a.y*b.x - a.x*b.y);
}
__device__ __forceinline__ float2 cadd(float2 a, float2 b){ return make_float2(a.x+b.x, a.y+b.y); }
__device__ __forceinline__ float2 csub(float2 a, float2 b){ return make_float2(a.x-b.x, a.y-b.y); }
// e^{i*pi*a}
__device__ __forceinline__ float2 eipi(float a) {
    float s, c;
    sincospif(a, &s, &c);
    return make_float2(c, s);
}

#define C1f 0.30901699437494742f
#define C2f (-0.80901699437494745f)
#define S1f 0.95105651629515357f
#define S2f 0.58778525229247314f

// forward (DIF) radix-5 butterfly, in place, no twiddles
__device__ __forceinline__ void bfly5_fwd(float2& e0, float2& e1, float2& e2,
                                          float2& e3, float2& e4) {
    float2 t1 = cadd(e1, e4), t2 = cadd(e2, e3);
    float2 t3 = csub(e1, e4), t4 = csub(e2, e3);
    float2 f0 = make_float2(e0.x + t1.x + t2.x, e0.y + t1.y + t2.y);
    float2 m1 = make_float2(e0.x + C1f*t1.x + C2f*t2.x, e0.y + C1f*t1.y + C2f*t2.y);
    float2 m2 = make_float2(e0.x + C2f*t1.x + C1f*t2.x, e0.y + C2f*t1.y + C1f*t2.y);
    float2 v1 = make_float2(S1f*t3.x + S2f*t4.x, S1f*t3.y + S2f*t4.y);
    float2 v2 = make_float2(S2f*t3.x - S1f*t4.x, S2f*t3.y - S1f*t4.y);
    e0 = f0;
    e1 = make_float2(m1.x + v1.y, m1.y - v1.x);   // m1 - i v1
    e4 = make_float2(m1.x - v1.y, m1.y + v1.x);   // m1 + i v1
    e2 = make_float2(m2.x + v2.y, m2.y - v2.x);   // m2 - i v2
    e3 = make_float2(m2.x - v2.y, m2.y + v2.x);   // m2 + i v2
}
// inverse (DIT) radix-5 butterfly, in place, no twiddles
__device__ __forceinline__ void bfly5_inv(float2& e0, float2& e1, float2& e2,
                                          float2& e3, float2& e4) {
    float2 t1 = cadd(e1, e4), t2 = cadd(e2, e3);
    float2 t3 = csub(e1, e4), t4 = csub(e2, e3);
    float2 f0 = make_float2(e0.x + t1.x + t2.x, e0.y + t1.y + t2.y);
    float2 m1 = make_float2(e0.x + C1f*t1.x + C2f*t2.x, e0.y + C1f*t1.y + C2f*t2.y);
    float2 m2 = make_float2(e0.x + C2f*t1.x + C1f*t2.x, e0.y + C2f*t1.y + C1f*t2.y);
    float2 v1 = make_float2(S1f*t3.x + S2f*t4.x, S1f*t3.y + S2f*t4.y);
    float2 v2 = make_float2(S2f*t3.x - S1f*t4.x, S2f*t3.y - S1f*t4.y);
    e0 = f0;
    e1 = make_float2(m1.x - v1.y, m1.y + v1.x);   // m1 + i v1
    e4 = make_float2(m1.x + v1.y, m1.y - v1.x);   // m1 - i v1
    e2 = make_float2(m2.x - v2.y, m2.y + v2.x);   // m2 + i v2
    e3 = make_float2(m2.x + v2.y, m2.y - v2.x);   // m2 - i v2
}

// Cross-twiddle LUT: Wc[p] = exp(-2*pi*i * c * brev7(r) / N), p = r*125 + c
__global__ void fill_cross_lut(float2* __restrict__ ws) {
    int p = blockIdx.x * 256 + threadIdx.x;
    if (p < NFFT) {
        int r  = p / NCCOL;
        int c  = p - r * NCCOL;
        int k1 = __brev((unsigned)r) >> 25;
        ws[p]  = eipi((float)(c * k1) * (-2.0f / (float)NFFT));
    }
}

// One block per batch row. LDS holds z[16000] complex + twiddle LUTs.
//
// 128-axis: radix-16 (F1': dist 64,32,16,8; rows j+8t) then radix-8 (F2':
// dist 4,2,1; rows 8g..8g+7). The middle (F2' -> cross -> F3 -> FSQ -> I2 ->
// conj cross -> I3') is local to an 8-row stripe; 16 stripes == 16 waves, so
// the middle runs with NO __syncthreads() (in-wave LDS RAW ordered by
// lgkmcnt). Barriers: 4 total.
//
// Column FFT (125 = 5^3) per stripe:
//   F3  = both L=125 and L=25 layers FUSED in one 25-element/item pass
//         (40 items/stripe) - one LDS round trip for two layers.
//   FSQ = forward L=5 + spectrum square + inverse L=5, 5-elem items (200).
//   I2  = inverse L=25 + L=125 fused (40 items).
// The 25-float2 working set fits the 128-VGPR budget pinned by
// amdgpu_waves_per_eu(4,4) (would spill at the default 64-reg tier).
__global__ void __launch_bounds__(TPB) __attribute__((amdgpu_waves_per_eu(4, 4)))
mcb_fft_conv_kernel(const float* __restrict__ img, const float* __restrict__ seq,
                    const int* __restrict__ hvec, const float* __restrict__ svec,
                    float* __restrict__ out, const float2* __restrict__ cross)
{
    extern __shared__ float2 buf[];
    const int tid = threadIdx.x;
    const int b   = blockIdx.x;

    #define W2L(k) buf[R2OFF + (k)]
    #define R5L(k) buf[R5OFF + (k)]

    auto CW = [&](int row, int c) -> float2 {
        if (cross) return cross[row * NCCOL + c];
        int k1 = __brev((unsigned)row) >> 25;
        return eipi((float)(c * k1) * (-2.0f / (float)NFFT));
    };

    // ---- zero (vectorized) + build LDS twiddle LUTs
    {
        float4* b4 = (float4*)buf;                 // 16000 float2 = 8000 float4
        for (int p = tid; p < NFFT / 2; p += TPB) b4[p] = make_float4(0.f, 0.f, 0.f, 0.f);
    }
    if (tid < 64) {
        W2L(tid) = eipi(-(float)tid * (1.0f / 64.0f));        // w_128^j
    } else if (tid < 64 + 125) {
        int k = tid - 64;
        R5L(k) = eipi((float)k * (-2.0f / 125.0f));           // w_125^k
    }
    __syncthreads();

    // ---- count-sketch scatter (img -> re, seq -> im)
    {
        const float* irow = img + (size_t)b * DFEAT;
        const float* qrow = seq + (size_t)b * DFEAT;
        #pragma unroll
        for (int it = 0; it < DFEAT / TPB; ++it) {
            const int j = tid + (it << 10);
            float sj = svec[j];
            int   hj = hvec[j];
            atomicAdd(&buf[hj].x, irow[j] * sj);
            atomicAdd(&buf[hj].y, qrow[j] * sj);
        }
    }
    __syncthreads();

    // ======== F1': forward radix-16, dist 64,32,16,8 (rows j+8t, j=0..7) ========
    if (tid < 8 * NCCOL) {
        const int j = tid / NCCOL;          // 0..7
        const int c = tid - j * NCCOL;
        const int base = j * NCCOL + c;
        float2 x[16];
        #pragma unroll
        for (int t = 0; t < 16; ++t) x[t] = buf[base + 1000 * t];
        // H=64 (pairs t, t+8): twiddle w128^{j+8t}, t=0..7
        #pragma unroll
        for (int t = 0; t < 8; ++t) {
            float2 u = x[t], v = x[t+8];
            x[t]   = cadd(u, v);
            x[t+8] = cmul(csub(u, v), W2L(j + 8*t));
        }
        // H=32 (pairs q+t, q+t+4), q in {0,8}: twiddle w128^{2(j+8t)}, t=0..3
        #pragma unroll
        for (int q = 0; q < 16; q += 8)
            #pragma unroll
            for (int t = 0; t < 4; ++t) {
                float2 u = x[q+t], v = x[q+t+4];
                x[q+t]   = cadd(u, v);
                x[q+t+4] = cmul(csub(u, v), W2L(2*(j + 8*t)));
            }
        // H=16 (pairs q+t, q+t+2), q in {0,4,8,12}: twiddle w128^{4(j+8t)}, t=0,1
        #pragma unroll
        for (int q = 0; q < 16; q += 4)
            #pragma unroll
            for (int t = 0; t < 2; ++t) {
                float2 u = x[q+t], v = x[q+t+2];
                x[q+t]   = cadd(u, v);
                x[q+t+2] = cmul(csub(u, v), W2L(4*(j + 8*t)));
            }
        // H=8 (pairs q, q+1): twiddle w128^{8j}
        {
            float2 w = W2L(8*j);
            #pragma unroll
            for (int q = 0; q < 16; q += 2) {
                float2 u = x[q], v = x[q+1];
                x[q]   = cadd(u, v);
                x[q+1] = cmul(csub(u, v), w);
            }
        }
        #pragma unroll
        for (int t = 0; t < 16; ++t) buf[base + 1000 * t] = x[t];
    }
    __syncthreads();

    // ================= stripe-local middle: wave w owns rows 8w..8w+7 ==========
    {
        const int wv = tid >> 6;            // 0..15
        const int ln = tid & 63;
        const int rbase = wv * 8 * NCCOL;   // stripe base in LDS
        const int row0 = wv << 3;           // first row of stripe

        // ---- F2': forward radix-8, dist 4,2,1 + cross twiddle (rows 8wv+t)
        for (int c = ln; c < NCCOL; c += 64) {
            const int base = rbase + c;
            float2 x[8];
            #pragma unroll
            for (int t = 0; t < 8; ++t) x[t] = buf[base + NCCOL * t];
            // H=4 (pairs t, t+4): twiddle w128^{16t}, t=0..3
            #pragma unroll
            for (int t = 0; t < 4; ++t) {
                float2 u = x[t], v = x[t+4];
                x[t]   = cadd(u, v);
                x[t+4] = cmul(csub(u, v), W2L(16*t));
            }
            // H=2 (pairs q+t, q+t+2): twiddle w128^{32t}, t=0,1
            #pragma unroll
            for (int q = 0; q < 8; q += 4)
                #pragma unroll
                for (int t = 0; t < 2; ++t) {
                    float2 u = x[q+t], v = x[q+t+2];
                    x[q+t]   = cadd(u, v);
                    x[q+t+2] = cmul(csub(u, v), W2L(32*t));
                }
            // H=1 (pairs q, q+1): twiddle 1
            #pragma unroll
            for (int q = 0; q < 8; q += 2) {
                float2 u = x[q], v = x[q+1];
                x[q]   = cadd(u, v);
                x[q+1] = csub(u, v);
            }
            // cross twiddle (row 8wv+t, col c)
            #pragma unroll
            for (int t = 0; t < 8; ++t)
                buf[base + NCCOL * t] = cmul(x[t], CW(row0 + t, c));
        }

        // ---- F3: forward radix-5 L=125 + L=25 FUSED (items (r_loc, j2), 25 elems)
        if (ln < 40) {
            const int rl = ln / 5;          // 0..7
            const int j2 = ln - rl * 5;     // 0..4
            const int base = rbase + rl * NCCOL + j2;
            float2 x[25];
            #pragma unroll
            for (int q = 0; q < 25; ++q) x[q] = buf[base + 5 * q];
            // L=125: butterfly over k (elements j2+5p+25k) for each p
            #pragma unroll
            for (int p = 0; p < 5; ++p) {
                bfly5_fwd(x[p], x[p+5], x[p+10], x[p+15], x[p+20]);
                const int jw = j2 + 5*p;
                x[p+5]  = cmul(x[p+5],  R5L(jw));
                x[p+10] = cmul(x[p+10], R5L(2*jw));
                x[p+15] = cmul(x[p+15], R5L(3*jw));
                x[p+20] = cmul(x[p+20], R5L(4*jw));
            }
            // L=25: butterfly over p for each t5; twiddles hoisted (same for all t5)
            {
                const float2 wa = R5L(5*j2),  wb = R5L(10*j2),
                             wc = R5L(15*j2), wd = R5L(20*j2);
                #pragma unroll
                for (int t5 = 0; t5 < 5; ++t5) {
                    bfly5_fwd(x[5*t5], x[1+5*t5], x[2+5*t5], x[3+5*t5], x[4+5*t5]);
                    x[1+5*t5] = cmul(x[1+5*t5], wa);
                    x[2+5*t5] = cmul(x[2+5*t5], wb);
                    x[3+5*t5] = cmul(x[3+5*t5], wc);
                    x[4+5*t5] = cmul(x[4+5*t5], wd);
                }
            }
            #pragma unroll
            for (int q = 0; q < 25; ++q) buf[base + 5 * q] = x[q];
        }

        // ---- FSQ: forward L=5 + spectrum square + inverse L=5 (5-elem items)
        for (int idx = ln; idx < 200; idx += 64) {
            const int rl = idx / 25;
            const int q  = idx - rl * 25;
            const int base = rbase + rl * NCCOL + 5 * q;
            float2 g0 = buf[base], g1 = buf[base+1], g2 = buf[base+2],
                   g3 = buf[base+3], g4 = buf[base+4];
            bfly5_fwd(g0, g1, g2, g3, g4);
            g0 = make_float2(g0.x*g0.x - g0.y*g0.y, 2.f*g0.x*g0.y);
            g1 = make_float2(g1.x*g1.x - g1.y*g1.y, 2.f*g1.x*g1.y);
            g2 = make_float2(g2.x*g2.x - g2.y*g2.y, 2.f*g2.x*g2.y);
            g3 = make_float2(g3.x*g3.x - g3.y*g3.y, 2.f*g3.x*g3.y);
            g4 = make_float2(g4.x*g4.x - g4.y*g4.y, 2.f*g4.x*g4.y);
            bfly5_inv(g0, g1, g2, g3, g4);
            buf[base] = g0; buf[base+1] = g1; buf[base+2] = g2;
            buf[base+3] = g3; buf[base+4] = g4;
        }

        // ---- I2: inverse radix-5 L=25 + L=125 FUSED (items (r_loc, j2), 25 elems)
        if (ln < 40) {
            const int rl = ln / 5;
            const int j2 = ln - rl * 5;
            const int base = rbase + rl * NCCOL + j2;
            float2 x[25];
            #pragma unroll
            for (int q = 0; q < 25; ++q) x[q] = buf[base + 5 * q];
            // L=25 DIT: conj twiddle then inverse butterfly over p (per t5)
            {
                const float2 wa = R5L(5*j2),  wb = R5L(10*j2),
                             wc = R5L(15*j2), wd = R5L(20*j2);
                #pragma unroll
                for (int t5 = 0; t5 < 5; ++t5) {
                    x[1+5*t5] = cmulc(x[1+5*t5], wa);
                    x[2+5*t5] = cmulc(x[2+5*t5], wb);
                    x[3+5*t5] = cmulc(x[3+5*t5], wc);
                    x[4+5*t5] = cmulc(x[4+5*t5], wd);
                    bfly5_inv(x[5*t5], x[1+5*t5], x[2+5*t5], x[3+5*t5], x[4+5*t5]);
                }
            }
            // L=125 DIT: conj twiddle then inverse butterfly over k (per p)
            #pragma unroll
            for (int p = 0; p < 5; ++p) {
                const int jw = j2 + 5*p;
                x[p+5]  = cmulc(x[p+5],  R5L(jw));
                x[p+10] = cmulc(x[p+10], R5L(2*jw));
                x[p+15] = cmulc(x[p+15], R5L(3*jw));
                x[p+20] = cmulc(x[p+20], R5L(4*jw));
                bfly5_inv(x[p], x[p+5], x[p+10], x[p+15], x[p+20]);
            }
            #pragma unroll
            for (int q = 0; q < 25; ++q) buf[base + 5 * q] = x[q];
        }

        // ---- I3': conj cross + inverse radix-8, dist 1,2,4 (rows 8wv+t)
        for (int c = ln; c < NCCOL; c += 64) {
            const int base = rbase + c;
            float2 x[8];
            #pragma unroll
            for (int t = 0; t < 8; ++t)
                x[t] = cmulc(buf[base + NCCOL * t], CW(row0 + t, c));
            // H=1 (pairs q, q+1): twiddle 1
            #pragma unroll
            for (int q = 0; q < 8; q += 2) {
                float2 u = x[q], v = x[q+1];
                x[q]   = cadd(u, v);
                x[q+1] = csub(u, v);
            }
            // H=2: conj w128^{32t}, t=0,1
            #pragma unroll
            for (int q = 0; q < 8; q += 4)
                #pragma unroll
                for (int t = 0; t < 2; ++t) {
                    float2 u = x[q+t];
                    float2 v = cmulc(x[q+t+2], W2L(32*t));
                    x[q+t]   = cadd(u, v);
                    x[q+t+2] = csub(u, v);
                }
            // H=4: conj w128^{16t}, t=0..3
            #pragma unroll
            for (int t = 0; t < 4; ++t) {
                float2 u = x[t];
                float2 v = cmulc(x[t+4], W2L(16*t));
                x[t]   = cadd(u, v);
                x[t+4] = csub(u, v);
            }
            #pragma unroll
            for (int t = 0; t < 8; ++t) buf[base + NCCOL * t] = x[t];
        }
    }
    __syncthreads();

    // ======== I4': inverse radix-16, dist 8,16,32,64 + output (rows j+8t) ========
    const float scale = 1.0f / (2.0f * (float)NFFT);
    float* orow = out + (size_t)b * NFFT;
    if (tid < 8 * NCCOL) {
        const int j = tid / NCCOL;          // 0..7
        const int c = tid - j * NCCOL;
        const int base = j * NCCOL + c;
        float2 x[16];
        #pragma unroll
        for (int t = 0; t < 16; ++t) x[t] = buf[base + 1000 * t];
        // H=8 (pairs q, q+1): conj w128^{8j}
        {
            float2 w = W2L(8*j);
            #pragma unroll
            for (int q = 0; q < 16; q += 2) {
                float2 u = x[q];
                float2 v = cmulc(x[q+1], w);
                x[q]   = cadd(u, v);
                x[q+1] = csub(u, v);
            }
        }
        // H=16 (pairs q+t, q+t+2): conj w128^{4(j+8t)}, t=0,1
        #pragma unroll
        for (int q = 0; q < 16; q += 4)
            #pragma unroll
            for (int t = 0; t < 2; ++t) {
                float2 u = x[q+t];
                float2 v = cmulc(x[q+t+2], W2L(4*(j + 8*t)));
                x[q+t]   = cadd(u, v);
                x[q+t+2] = csub(u, v);
            }
        // H=32 (pairs q+t, q+t+4), q in {0,8}: conj w128^{2(j+8t)}, t=0..3
        #pragma unroll
        for (int q = 0; q < 16; q += 8)
            #pragma unroll
            for (int t = 0; t < 4; ++t) {
                float2 u = x[q+t];
                float2 v = cmulc(x[q+t+4], W2L(2*(j + 8*t)));
                x[q+t]   = cadd(u, v);
                x[q+t+4] = csub(u, v);
            }
        // H=64 (pairs t, t+8): conj w128^{j+8t}, t=0..7 — emit Im*scale
        #pragma unroll
        for (int t = 0; t < 8; ++t) {
            float2 u = x[t];
            float2 v = cmulc(x[t+8], W2L(j + 8*t));
            orow[base + 1000 * t]        = (u.y + v.y) * scale;
            orow[base + 1000 * t + 8000] = (u.y - v.y) * scale;
        }
    }
}

extern "C" void kernel_launch(void* const* d_in, const int* in_sizes, int n_in,
                              void* d_out, int out_size, void* d_ws, size_t ws_size,
                              hipStream_t stream)
{
    const float* img  = (const float*)d_in[0];
    const float* seq  = (const float*)d_in[1];
    const int*   hvec = (const int*)d_in[2];
    const float* svec = (const float*)d_in[3];
    float* out = (float*)d_out;

    const int B = in_sizes[0] / DFEAT;   // 2048
    const size_t lds_bytes = (size_t)LDSN * sizeof(float2);  // 129512 B

    const bool use_lut = ws_size >= (size_t)NFFT * sizeof(float2);
    float2* cross = use_lut ? (float2*)d_ws : nullptr;
    if (use_lut) {
        hipLaunchKernelGGL(fill_cross_lut, dim3((NFFT + 255) / 256), dim3(256), 0, stream,
                           cross);
    }

    hipFuncSetAttribute((const void*)mcb_fft_conv_kernel,
                        hipFuncAttributeMaxDynamicSharedMemorySize,
                        (int)lds_bytes);

    hipLaunchKernelGGL(mcb_fft_conv_kernel, dim3(B), dim3(TPB), lds_bytes, stream,
                       img, seq, hvec, svec, out, cross);
}

// Round 6
// 348.699 us; speedup vs baseline: 1.3838x; 1.3838x over previous
//
#include <hip/hip_runtime.h>
#include <math.h>

#define NFFT  16000   // = 128 * 125
#define NCCOL 125     // radix-5 axis (contiguous)
#define DFEAT 2048
#define TPB   1024
#define R2OFF 16000   // LDS offset: 64-entry w_128^j LUT (forward sign)
#define R5OFF 16064   // LDS offset: 125-entry w_125^k LUT (forward sign)
#define LDSN  16189   // total float2 elements in LDS

// Packed complex: <2 x float> so clang ISel can emit v_pk_{add,mul,fma}_f32
// (gfx90a+). Scalar .x/.y float2 math does NOT get re-vectorized by hipcc.
typedef float v2f __attribute__((ext_vector_type(2)));

__device__ __forceinline__ v2f cmul(v2f a, v2f b) {
    v2f t  = a.x * b;                                   // {ax*bx, ax*by}
    v2f bs = __builtin_shufflevector(b, b, 1, 0);       // {by, bx}
    v2f u  = a.y * bs;                                  // {ay*by, ay*bx}
    v2f r;
    r.x = t.x - u.x;
    r.y = t.y + u.y;
    return r;
}
__device__ __forceinline__ v2f cmulc(v2f a, v2f b) {    // a * conj(b)
    v2f t  = a.x * b;                                   // {ax*bx, ax*by}
    v2f bs = __builtin_shufflevector(b, b, 1, 0);       // {by, bx}
    v2f u  = a.y * bs;                                  // {ay*by, ay*bx}
    v2f r;
    r.x = t.x + u.x;
    r.y = u.y - t.y;
    return r;
}
// m - i*v  and  m + i*v (the butterfly recombines)
__device__ __forceinline__ v2f subi(v2f m, v2f v) {
    v2f vs = __builtin_shufflevector(v, v, 1, 0);       // {v.y, v.x}
    v2f r;
    r.x = m.x + vs.x;
    r.y = m.y - vs.y;
    return r;
}
__device__ __forceinline__ v2f addi(v2f m, v2f v) {
    v2f vs = __builtin_shufflevector(v, v, 1, 0);
    v2f r;
    r.x = m.x - vs.x;
    r.y = m.y + vs.y;
    return r;
}
// e^{i*pi*a}
__device__ __forceinline__ v2f eipi(float a) {
    float s, c;
    sincospif(a, &s, &c);
    v2f r; r.x = c; r.y = s;
    return r;
}

#define C1f 0.30901699437494742f
#define C2f (-0.80901699437494745f)
#define S1f 0.95105651629515357f
#define S2f 0.58778525229247314f

// forward (DIF) radix-5 butterfly, in place, no twiddles
__device__ __forceinline__ void bfly5_fwd(v2f& e0, v2f& e1, v2f& e2,
                                          v2f& e3, v2f& e4) {
    v2f t1 = e1 + e4, t2 = e2 + e3;
    v2f t3 = e1 - e4, t4 = e2 - e3;
    v2f f0 = e0 + t1 + t2;
    v2f m1 = e0 + C1f * t1 + C2f * t2;
    v2f m2 = e0 + C2f * t1 + C1f * t2;
    v2f v1 = S1f * t3 + S2f * t4;
    v2f v2 = S2f * t3 - S1f * t4;
    e0 = f0;
    e1 = subi(m1, v1);   // m1 - i v1
    e4 = addi(m1, v1);   // m1 + i v1
    e2 = subi(m2, v2);   // m2 - i v2
    e3 = addi(m2, v2);   // m2 + i v2
}
// inverse (DIT) radix-5 butterfly, in place, no twiddles
__device__ __forceinline__ void bfly5_inv(v2f& e0, v2f& e1, v2f& e2,
                                          v2f& e3, v2f& e4) {
    v2f t1 = e1 + e4, t2 = e2 + e3;
    v2f t3 = e1 - e4, t4 = e2 - e3;
    v2f f0 = e0 + t1 + t2;
    v2f m1 = e0 + C1f * t1 + C2f * t2;
    v2f m2 = e0 + C2f * t1 + C1f * t2;
    v2f v1 = S1f * t3 + S2f * t4;
    v2f v2 = S2f * t3 - S1f * t4;
    e0 = f0;
    e1 = addi(m1, v1);   // m1 + i v1
    e4 = subi(m1, v1);   // m1 - i v1
    e2 = addi(m2, v2);   // m2 + i v2
    e3 = subi(m2, v2);   // m2 - i v2
}

// Cross-twiddle LUT: Wc[p] = exp(-2*pi*i * c * brev7(r) / N), p = r*125 + c
__global__ void fill_cross_lut(v2f* __restrict__ ws) {
    int p = blockIdx.x * 256 + threadIdx.x;
    if (p < NFFT) {
        int r  = p / NCCOL;
        int c  = p - r * NCCOL;
        int k1 = __brev((unsigned)r) >> 25;
        ws[p]  = eipi((float)(c * k1) * (-2.0f / (float)NFFT));
    }
}

// One block per batch row. LDS holds z[16000] complex + twiddle LUTs.
// Forward: z = sk_img + i*sk_seq ; Z = FFT(z) (DIF four-step 128x125,
//          radix-8 + radix-16(+cross) on the 128 axis, radix-5^3 on 125)
// FSQ: forward L=5 + spectrum square + inverse L=5, one fused contiguous pass
// Inverse: mirror DIT, natural-order output; out = Im(w)/(2N) fused into last pass.
//
// Structure = round-2 best (273 us steady): block-wide barriers, stride 125,
// radix-25 passes UNFUSED into radix-5 pairs (verified twice: register items
// >16 float2 spill to scratch at this toolchain's hard 64-VGPR tier).
// This round: all complex math on ext_vector_type(2) so the VALU issues
// packed v_pk_*_f32 ops (~half the butterfly instruction count).
__global__ void __launch_bounds__(TPB) __attribute__((amdgpu_waves_per_eu(4, 4)))
mcb_fft_conv_kernel(const float* __restrict__ img, const float* __restrict__ seq,
                    const int* __restrict__ hvec, const float* __restrict__ svec,
                    float* __restrict__ out, const v2f* __restrict__ cross)
{
    extern __shared__ v2f buf[];
    const int tid = threadIdx.x;
    const int b   = blockIdx.x;

    #define W2L(k) buf[R2OFF + (k)]
    #define R5L(k) buf[R5OFF + (k)]

    auto CW = [&](int p) -> v2f {
        if (cross) return cross[p];
        int r = p / NCCOL, c = p - r * NCCOL;
        int k1 = __brev((unsigned)r) >> 25;
        return eipi((float)(c * k1) * (-2.0f / (float)NFFT));
    };

    // ---- zero (vectorized) + build LDS twiddle LUTs
    {
        float4* b4 = (float4*)buf;                 // 16000 v2f = 8000 float4
        for (int p = tid; p < NFFT / 2; p += TPB) b4[p] = make_float4(0.f, 0.f, 0.f, 0.f);
    }
    if (tid < 64) {
        W2L(tid) = eipi(-(float)tid * (1.0f / 64.0f));        // w_128^j
    } else if (tid < 64 + 125) {
        int k = tid - 64;
        R5L(k) = eipi((float)k * (-2.0f / 125.0f));           // w_125^k
    }
    __syncthreads();

    // ---- count-sketch scatter (img -> re, seq -> im)
    {
        float* bufs = (float*)buf;   // scalar alias (can't address vector lanes)
        const float* irow = img + (size_t)b * DFEAT;
        const float* qrow = seq + (size_t)b * DFEAT;
        #pragma unroll
        for (int it = 0; it < DFEAT / TPB; ++it) {
            const int j = tid + (it << 10);
            float sj = svec[j];
            int   hj = hvec[j];
            atomicAdd(&bufs[2 * hj],     irow[j] * sj);
            atomicAdd(&bufs[2 * hj + 1], qrow[j] * sj);
        }
    }
    __syncthreads();

    // ======== F1: forward radix-8, stages ls=6,5,4  (rows j + 16t) ========
    for (int idx = tid; idx < 16 * NCCOL; idx += TPB) {
        const int j = idx / NCCOL;          // 0..15
        const int c = idx - j * NCCOL;
        const int base = j * NCCOL + c;
        v2f x[8];
        #pragma unroll
        for (int t = 0; t < 8; ++t) x[t] = buf[base + 2000 * t];
        // ls=6 (dist 4): twiddle w128^{j+16t}
        #pragma unroll
        for (int t = 0; t < 4; ++t) {
            v2f u = x[t], v = x[t+4];
            x[t]   = u + v;
            x[t+4] = cmul(u - v, W2L(j + 16*t));
        }
        // ls=5 (dist 2): twiddle w128^{2(j+16t)}, t=0,1
        #pragma unroll
        for (int q = 0; q < 8; q += 4)
            #pragma unroll
            for (int t = 0; t < 2; ++t) {
                v2f u = x[q+t], v = x[q+t+2];
                x[q+t]   = u + v;
                x[q+t+2] = cmul(u - v, W2L(2*(j + 16*t)));
            }
        // ls=4 (dist 1): twiddle w128^{4j}
        {
            v2f w = W2L(4*j);
            #pragma unroll
            for (int q = 0; q < 8; q += 2) {
                v2f u = x[q], v = x[q+1];
                x[q]   = u + v;
                x[q+1] = cmul(u - v, w);
            }
        }
        #pragma unroll
        for (int t = 0; t < 8; ++t) buf[base + 2000 * t] = x[t];
    }
    __syncthreads();

    // ======== F2: forward radix-16, stages ls=3..0 + cross twiddle (rows 16g+t) ====
    for (int idx = tid; idx < 8 * NCCOL; idx += TPB) {
        const int g = idx / NCCOL;          // 0..7
        const int c = idx - g * NCCOL;
        const int base = 2000 * g + c;
        v2f x[16];
        #pragma unroll
        for (int t = 0; t < 16; ++t) x[t] = buf[base + 125 * t];
        // ls=3 (dist 8): twiddle w128^{8t}
        #pragma unroll
        for (int t = 0; t < 8; ++t) {
            v2f u = x[t], v = x[t+8];
            x[t]   = u + v;
            x[t+8] = cmul(u - v, W2L(8*t));
        }
        // ls=2 (dist 4): twiddle w128^{16t}, t=0..3
        #pragma unroll
        for (int q = 0; q < 16; q += 8)
            #pragma unroll
            for (int t = 0; t < 4; ++t) {
                v2f u = x[q+t], v = x[q+t+4];
                x[q+t]   = u + v;
                x[q+t+4] = cmul(u - v, W2L(16*t));
            }
        // ls=1 (dist 2): twiddle w128^{32t}, t=0,1
        #pragma unroll
        for (int q = 0; q < 16; q += 4)
            #pragma unroll
            for (int t = 0; t < 2; ++t) {
                v2f u = x[q+t], v = x[q+t+2];
                x[q+t]   = u + v;
                x[q+t+2] = cmul(u - v, W2L(32*t));
            }
        // ls=0 (dist 1): twiddle 1
        #pragma unroll
        for (int q = 0; q < 16; q += 2) {
            v2f u = x[q], v = x[q+1];
            x[q]   = u + v;
            x[q+1] = u - v;
        }
        // cross twiddle (element at row 16g+t has flat index base + 125t)
        #pragma unroll
        for (int t = 0; t < 16; ++t)
            buf[base + 125 * t] = cmul(x[t], CW(base + 125 * t));
    }
    __syncthreads();

    // ======== F3a: forward radix-5, span 25 (items (r, m), m = c mod 25) ========
    for (int idx = tid; idx < 128 * 25; idx += TPB) {
        const int r = idx / 25;
        const int m = idx - r * 25;
        const int base = r * NCCOL + m;
        v2f x0 = buf[base],      x1 = buf[base + 25], x2 = buf[base + 50],
            x3 = buf[base + 75], x4 = buf[base + 100];
        bfly5_fwd(x0, x1, x2, x3, x4);
        x1 = cmul(x1, R5L(m));
        x2 = cmul(x2, R5L(2*m));
        x3 = cmul(x3, R5L(3*m));
        x4 = cmul(x4, R5L(4*m));
        buf[base] = x0; buf[base + 25] = x1; buf[base + 50] = x2;
        buf[base + 75] = x3; buf[base + 100] = x4;
    }
    __syncthreads();

    // ======== F3b: forward radix-5, span 5 (items (r, j2, t5)) ========
    for (int idx = tid; idx < 128 * 25; idx += TPB) {
        const int r  = idx / 25;
        const int s  = idx - r * 25;
        const int t5 = s / 5;
        const int j2 = s - t5 * 5;
        const int base = r * NCCOL + j2 + 25 * t5;
        v2f x0 = buf[base],      x1 = buf[base + 5],  x2 = buf[base + 10],
            x3 = buf[base + 15], x4 = buf[base + 20];
        bfly5_fwd(x0, x1, x2, x3, x4);
        x1 = cmul(x1, R5L(5*j2));
        x2 = cmul(x2, R5L(10*j2));
        x3 = cmul(x3, R5L(15*j2));
        x4 = cmul(x4, R5L(20*j2));
        buf[base] = x0; buf[base + 5] = x1; buf[base + 10] = x2;
        buf[base + 15] = x3; buf[base + 20] = x4;
    }
    __syncthreads();

    // ======== FSQ: forward L=5 + spectrum square + inverse L=5 (fused) ========
    for (int idx = tid; idx < 128 * 25; idx += TPB) {
        const int r = idx / 25;
        const int q = idx - r * 25;
        const int base = r * NCCOL + 5 * q;
        v2f g0 = buf[base], g1 = buf[base+1], g2 = buf[base+2],
            g3 = buf[base+3], g4 = buf[base+4];
        bfly5_fwd(g0, g1, g2, g3, g4);                      // forward stage L=5
        g0 = cmul(g0, g0);                                  // Z^2
        g1 = cmul(g1, g1);
        g2 = cmul(g2, g2);
        g3 = cmul(g3, g3);
        g4 = cmul(g4, g4);
        bfly5_inv(g0, g1, g2, g3, g4);                      // inverse stage L=5
        buf[base] = g0; buf[base+1] = g1; buf[base+2] = g2;
        buf[base+3] = g3; buf[base+4] = g4;
    }
    __syncthreads();

    // ======== I2a: inverse radix-5, span 5 (items (r, j2, t5)) ========
    for (int idx = tid; idx < 128 * 25; idx += TPB) {
        const int r  = idx / 25;
        const int s  = idx - r * 25;
        const int t5 = s / 5;
        const int j2 = s - t5 * 5;
        const int base = r * NCCOL + j2 + 25 * t5;
        v2f x0 = buf[base],      x1 = buf[base + 5],  x2 = buf[base + 10],
            x3 = buf[base + 15], x4 = buf[base + 20];
        x1 = cmulc(x1, R5L(5*j2));
        x2 = cmulc(x2, R5L(10*j2));
        x3 = cmulc(x3, R5L(15*j2));
        x4 = cmulc(x4, R5L(20*j2));
        bfly5_inv(x0, x1, x2, x3, x4);
        buf[base] = x0; buf[base + 5] = x1; buf[base + 10] = x2;
        buf[base + 15] = x3; buf[base + 20] = x4;
    }
    __syncthreads();

    // ======== I2b: inverse radix-5, span 25 (items (r, m)) ========
    for (int idx = tid; idx < 128 * 25; idx += TPB) {
        const int r = idx / 25;
        const int m = idx - r * 25;
        const int base = r * NCCOL + m;
        v2f x0 = buf[base],      x1 = buf[base + 25], x2 = buf[base + 50],
            x3 = buf[base + 75], x4 = buf[base + 100];
        x1 = cmulc(x1, R5L(m));
        x2 = cmulc(x2, R5L(2*m));
        x3 = cmulc(x3, R5L(3*m));
        x4 = cmulc(x4, R5L(4*m));
        bfly5_inv(x0, x1, x2, x3, x4);
        buf[base] = x0; buf[base + 25] = x1; buf[base + 50] = x2;
        buf[base + 75] = x3; buf[base + 100] = x4;
    }
    __syncthreads();

    // ======== I3: inverse radix-16: conj cross + stages ls=0..3 (rows 16g+t) ====
    for (int idx = tid; idx < 8 * NCCOL; idx += TPB) {
        const int g = idx / NCCOL;
        const int c = idx - g * NCCOL;
        const int base = 2000 * g + c;
        v2f x[16];
        #pragma unroll
        for (int t = 0; t < 16; ++t)
            x[t] = cmulc(buf[base + 125 * t], CW(base + 125 * t));
        // ls=0 (dist 1): twiddle 1
        #pragma unroll
        for (int q = 0; q < 16; q += 2) {
            v2f u = x[q], v = x[q+1];
            x[q]   = u + v;
            x[q+1] = u - v;
        }
        // ls=1 (dist 2): conj w128^{32t}
        #pragma unroll
        for (int q = 0; q < 16; q += 4)
            #pragma unroll
            for (int t = 0; t < 2; ++t) {
                v2f u = x[q+t];
                v2f v = cmulc(x[q+t+2], W2L(32*t));
                x[q+t]   = u + v;
                x[q+t+2] = u - v;
            }
        // ls=2 (dist 4): conj w128^{16t}
        #pragma unroll
        for (int q = 0; q < 16; q += 8)
            #pragma unroll
            for (int t = 0; t < 4; ++t) {
                v2f u = x[q+t];
                v2f v = cmulc(x[q+t+4], W2L(16*t));
                x[q+t]   = u + v;
                x[q+t+4] = u - v;
            }
        // ls=3 (dist 8): conj w128^{8t}
        #pragma unroll
        for (int t = 0; t < 8; ++t) {
            v2f u = x[t];
            v2f v = cmulc(x[t+8], W2L(8*t));
            x[t]   = u + v;
            x[t+8] = u - v;
        }
        #pragma unroll
        for (int t = 0; t < 16; ++t) buf[base + 125 * t] = x[t];
    }
    __syncthreads();

    // ======== I4: inverse radix-8, stages ls=4,5,6 + output write (rows j+16t) ====
    const float scale = 1.0f / (2.0f * (float)NFFT);
    float* orow = out + (size_t)b * NFFT;
    for (int idx = tid; idx < 16 * NCCOL; idx += TPB) {
        const int j = idx / NCCOL;
        const int c = idx - j * NCCOL;
        const int base = j * NCCOL + c;
        v2f x[8];
        #pragma unroll
        for (int t = 0; t < 8; ++t) x[t] = buf[base + 2000 * t];
        // ls=4 (dist 1): conj w128^{4j}
        {
            v2f w = W2L(4*j);
            #pragma unroll
            for (int q = 0; q < 8; q += 2) {
                v2f u = x[q];
                v2f v = cmulc(x[q+1], w);
                x[q]   = u + v;
                x[q+1] = u - v;
            }
        }
        // ls=5 (dist 2): conj w128^{2(j+16t)}, t=0,1
        #pragma unroll
        for (int q = 0; q < 8; q += 4)
            #pragma unroll
            for (int t = 0; t < 2; ++t) {
                v2f u = x[q+t];
                v2f v = cmulc(x[q+t+2], W2L(2*(j + 16*t)));
                x[q+t]   = u + v;
                x[q+t+2] = u - v;
            }
        // ls=6 (dist 4): conj w128^{j+16t}, t=0..3 — then emit Im*scale
        #pragma unroll
        for (int t = 0; t < 4; ++t) {
            v2f u = x[t];
            v2f v = cmulc(x[t+4], W2L(j + 16*t));
            orow[base + 2000 * t]       = (u.y + v.y) * scale;
            orow[base + 2000 * (t + 4)] = (u.y - v.y) * scale;
        }
    }
}

extern "C" void kernel_launch(void* const* d_in, const int* in_sizes, int n_in,
                              void* d_out, int out_size, void* d_ws, size_t ws_size,
                              hipStream_t stream)
{
    const float* img  = (const float*)d_in[0];
    const float* seq  = (const float*)d_in[1];
    const int*   hvec = (const int*)d_in[2];
    const float* svec = (const float*)d_in[3];
    float* out = (float*)d_out;

    const int B = in_sizes[0] / DFEAT;   // 2048
    const size_t lds_bytes = (size_t)LDSN * sizeof(v2f);  // 129512 B

    const bool use_lut = ws_size >= (size_t)NFFT * sizeof(v2f);
    v2f* cross = use_lut ? (v2f*)d_ws : nullptr;
    if (use_lut) {
        hipLaunchKernelGGL(fill_cross_lut, dim3((NFFT + 255) / 256), dim3(256), 0, stream,
                           cross);
    }

    hipFuncSetAttribute((const void*)mcb_fft_conv_kernel,
                        hipFuncAttributeMaxDynamicSharedMemorySize,
                        (int)lds_bytes);

    hipLaunchKernelGGL(mcb_fft_conv_kernel, dim3(B), dim3(TPB), lds_bytes, stream,
                       img, seq, hvec, svec, out, cross);
}